// Round 4
// baseline (178.533 us; speedup 1.0000x reference)
//
#include <hip/hip_runtime.h>
#include <math.h>

#define NPOS 4096
#define DCH  512
#define HD   32
#define NH   16
#define KW   9
#define DIL  3
#define PAD  12
#define TILE   128
#define NTILES (NPOS / TILE)       // 32
#define CSPL   8                   // channel-split lanes per token-group
#define CPT    (HD / CSPL)         // 4 channels per thread
#define TPT    4                   // tokens per thread
#define WSPAN  28                  // TPT + DIL*(KW-1) = 28 tokens per window
#define WCHK   (WSPAN / 4)         // 7 float4 chunks per row window (w0 % 4 == 0)

// Butterfly sum over 8 consecutive lanes — pure VALU via DPP.
// xor1 = quad_perm(1,0,3,2)=0xB1, xor2 = quad_perm(2,3,0,1)=0x4E,
// cross-quad within 8 = row_half_mirror (0x141).
__device__ __forceinline__ float dpp_sum8(float x) {
    int t;
    t = __builtin_amdgcn_update_dpp(0, __float_as_int(x), 0xB1, 0xF, 0xF, true);
    x += __int_as_float(t);
    t = __builtin_amdgcn_update_dpp(0, __float_as_int(x), 0x4E, 0xF, 0xF, true);
    x += __int_as_float(t);
    t = __builtin_amdgcn_update_dpp(0, __float_as_int(x), 0x141, 0xF, 0xF, true);
    x += __int_as_float(t);
    return x;
}

// Load a 28-float window (7 x global dwordx4) from a global row pointer.
__device__ __forceinline__ void load_w_global(const float* base, float* w) {
    const float4* wp = (const float4*)base;
#pragma unroll
    for (int u = 0; u < WCHK; ++u) {
        float4 x = wp[u];
        w[4*u] = x.x; w[4*u+1] = x.y; w[4*u+2] = x.z; w[4*u+3] = x.w;
    }
}

// Edge variant: per-chunk bounds check, clamped scalar fallback (values at
// invalid taps are garbage-but-finite; masked to zero in softmax).
__device__ __forceinline__ void load_w_clamped(const float* row, int w0, float* w) {
#pragma unroll
    for (int u = 0; u < WCHK; ++u) {
        int g0 = w0 + 4 * u;
        if (g0 >= 0 && g0 + 4 <= NPOS) {
            float4 x = *(const float4*)(row + g0);
            w[4*u] = x.x; w[4*u+1] = x.y; w[4*u+2] = x.z; w[4*u+3] = x.w;
        } else {
#pragma unroll
            for (int e = 0; e < 4; ++e) {
                int i = min(max(g0 + e, 0), NPOS - 1);
                w[4*u + e] = row[i];
            }
        }
    }
}

__global__ __launch_bounds__(256) void dilate_attn_kernel(
    const float* __restrict__ q,
    const float* __restrict__ k,
    const float* __restrict__ v,
    float* __restrict__ out)
{
    const int bh   = blockIdx.x >> 5;            // 0..63  (b*16+h)
    const int tile = blockIdx.x & (NTILES - 1);  // 0..31
    const int n0t  = tile * TILE;

    const int cs = threadIdx.x & (CSPL - 1);     // lane&7: channel octet slot
    const int lg = threadIdx.x >> 3;             // token group in tile
    const int n0 = n0t + lg * TPT;               // first token this thread owns
    const int w0 = n0 - PAD;                     // window start (multiple of 4)

    const size_t cb = (size_t)bh * HD * NPOS;
    const float* qg = q + cb;
    const float* kg = k + cb;
    const float* vg = v + cb;

    // easy <=> this thread's whole window is interior <=> all taps valid
    const bool easy = (w0 >= 0) && (w0 + WSPAN <= NPOS);
    const float scale = 0.17677669529663687f;    // 32^-0.5

    // ---------------- q: 4 x float4 (8 x 128B segments per wave) -----------
    float4 qv[CPT];
#pragma unroll
    for (int i = 0; i < CPT; ++i)
        qv[i] = *(const float4*)(qg + (size_t)(cs * CPT + i) * NPOS + n0);

    // ---------------- Pass 1: scores straight from global K ----------------
    float s[TPT][KW];
#pragma unroll
    for (int t = 0; t < TPT; ++t)
#pragma unroll
        for (int j = 0; j < KW; ++j) s[t][j] = 0.0f;

    if (easy) {
#pragma unroll
        for (int i = 0; i < CPT; ++i) {
            float w[WSPAN];
            load_w_global(kg + (size_t)(cs * CPT + i) * NPOS + w0, w);
            float qt[TPT] = {qv[i].x, qv[i].y, qv[i].z, qv[i].w};
#pragma unroll
            for (int t = 0; t < TPT; ++t)
#pragma unroll
                for (int j = 0; j < KW; ++j)
                    s[t][j] = fmaf(qt[t], w[t + 3*j], s[t][j]);
        }
    } else {
#pragma unroll
        for (int i = 0; i < CPT; ++i) {
            float w[WSPAN];
            load_w_clamped(kg + (size_t)(cs * CPT + i) * NPOS, w0, w);
            float qt[TPT] = {qv[i].x, qv[i].y, qv[i].z, qv[i].w};
#pragma unroll
            for (int t = 0; t < TPT; ++t)
#pragma unroll
                for (int j = 0; j < KW; ++j)
                    s[t][j] = fmaf(qt[t], w[t + 3*j], s[t][j]);
        }
    }

    // Reduce partial scores across the 8 channel-split lanes (DPP, no DS ops)
#pragma unroll
    for (int t = 0; t < TPT; ++t)
#pragma unroll
        for (int j = 0; j < KW; ++j)
            s[t][j] = dpp_sum8(s[t][j]);

    // ---------------- Softmax per token -------------------------------------
    if (easy) {
#pragma unroll
        for (int t = 0; t < TPT; ++t) {
            float m = -INFINITY;
#pragma unroll
            for (int j = 0; j < KW; ++j) {
                float x = s[t][j] * scale;
                s[t][j] = x;
                m = fmaxf(m, x);
            }
            float sum = 0.0f;
#pragma unroll
            for (int j = 0; j < KW; ++j) {
                float e = __expf(s[t][j] - m);
                s[t][j] = e;
                sum += e;
            }
            float inv = 1.0f / sum;
#pragma unroll
            for (int j = 0; j < KW; ++j) s[t][j] *= inv;
        }
    } else {
        // invalid taps: logit exactly 0 (matches Unfold zero-padding), prob
        // zeroed at the end
#pragma unroll
        for (int t = 0; t < TPT; ++t) {
            float vm[KW];
            float m = -INFINITY;
#pragma unroll
            for (int j = 0; j < KW; ++j) {
                vm[j] = ((unsigned)(n0 + t + 3*j - PAD) < NPOS) ? 1.0f : 0.0f;
                float x = s[t][j] * scale * vm[j];
                s[t][j] = x;
                m = fmaxf(m, x);
            }
            float sum = 0.0f;
#pragma unroll
            for (int j = 0; j < KW; ++j) {
                float e = __expf(s[t][j] - m);
                s[t][j] = e;
                sum += e;
            }
            float inv = 1.0f / sum;
#pragma unroll
            for (int j = 0; j < KW; ++j)
                s[t][j] *= inv * vm[j];          // s now holds probabilities
        }
    }

    // ---------------- Pass 2: output straight from global V ----------------
    float o[TPT][CPT];
#pragma unroll
    for (int t = 0; t < TPT; ++t)
#pragma unroll
        for (int i = 0; i < CPT; ++i) o[t][i] = 0.0f;

    if (easy) {
#pragma unroll
        for (int i = 0; i < CPT; ++i) {
            float w[WSPAN];
            load_w_global(vg + (size_t)(cs * CPT + i) * NPOS + w0, w);
#pragma unroll
            for (int t = 0; t < TPT; ++t)
#pragma unroll
                for (int j = 0; j < KW; ++j)
                    o[t][i] = fmaf(s[t][j], w[t + 3*j], o[t][i]);
        }
    } else {
#pragma unroll
        for (int i = 0; i < CPT; ++i) {
            float w[WSPAN];
            load_w_clamped(vg + (size_t)(cs * CPT + i) * NPOS, w0, w);
#pragma unroll
            for (int t = 0; t < TPT; ++t)
#pragma unroll
                for (int j = 0; j < KW; ++j)
                    o[t][i] = fmaf(s[t][j], w[t + 3*j], o[t][i]);
        }
    }

    // ---------------- Store: one float4 per token (octet -> 128B/token) ----
    const int b  = bh >> 4;
    const int hh = bh & (NH - 1);
#pragma unroll
    for (int t = 0; t < TPT; ++t) {
        float* op = out + ((size_t)(b * NPOS + n0 + t)) * DCH + hh * HD + cs * CPT;
        *(float4*)op = make_float4(o[t][0], o[t][1], o[t][2], o[t][3]);
    }
}

extern "C" void kernel_launch(void* const* d_in, const int* in_sizes, int n_in,
                              void* d_out, int out_size, void* d_ws, size_t ws_size,
                              hipStream_t stream) {
    const float* q = (const float*)d_in[0];
    const float* k = (const float*)d_in[1];
    const float* v = (const float*)d_in[2];
    float* out = (float*)d_out;

    const int grid = 4 * NH * NTILES;   // 64 bh * 32 tiles = 2048 blocks
    hipLaunchKernelGGL(dilate_attn_kernel, dim3(grid), dim3(256), 0, stream,
                       q, k, v, out);
}

// Round 5
// 141.482 us; speedup vs baseline: 1.2619x; 1.2619x over previous
//
#include <hip/hip_runtime.h>
#include <math.h>

#define NPOS 4096
#define DCH  512
#define HD   32
#define NH   16
#define KW   9
#define DIL  3
#define PAD  12
#define TILE   128
#define NTILES (NPOS / TILE)       // 32
#define TPB    4                   // tiles per block (pipeline depth 4)
#define NBLK   (NTILES / TPB)      // 8 blocks per bh
#define SPANT  (TILE + 2*PAD)      // 152 tokens staged per tile
#define SLDS   156                 // LDS row stride in floats (152 + 4 pad)
#define ROWC   (SLDS / 4)          // 39 16B chunks per row (incl pad chunk)
#define NCHK   (HD * ROWC)         // 1248 chunks per k (or v) tile
#define BUFSZ  (2 * HD * SLDS)     // floats per buffer set (k rows + v rows)
#define CSPL   8                   // channel-split lanes per token-group
#define CPT    (HD / CSPL)         // 4 channels per thread
#define TPT    4                   // tokens per thread
#define WSPAN  28                  // 4 tokens x 9 taps span 28 tokens

// Direct global->LDS (16B). LDS dest linear in lane; global src per-lane.
__device__ __forceinline__ void gload16(const float* g, float* l) {
    __builtin_amdgcn_global_load_lds(
        (const __attribute__((address_space(1))) void*)g,
        (__attribute__((address_space(3))) void*)l,
        16, 0, 0);
}

// Butterfly sum over 8 consecutive lanes — pure VALU via DPP.
__device__ __forceinline__ float dpp_sum8(float x) {
    int t;
    t = __builtin_amdgcn_update_dpp(0, __float_as_int(x), 0xB1, 0xF, 0xF, true);
    x += __int_as_float(t);
    t = __builtin_amdgcn_update_dpp(0, __float_as_int(x), 0x4E, 0xF, 0xF, true);
    x += __int_as_float(t);
    t = __builtin_amdgcn_update_dpp(0, __float_as_int(x), 0x141, 0xF, 0xF, true);
    x += __int_as_float(t);
    return x;
}

// Stage K,V span for one tile into a buffer set. Per-lane global addresses
// CLAMPED to [0, NPOS-4]: a chunk is clamped only if it lies fully in the
// pad region (all its taps invalid -> masked to zero in softmax), so valid
// taps always come from exact, unclamped chunks. 10 vmem inst per wave.
__device__ __forceinline__ void stage_kv(const float* kg, const float* vg,
                                         int ws, float* buf) {
#pragma unroll
    for (int it = 0; it < 5; ++it) {
        int c = it * 256 + (int)threadIdx.x;
        if (c < NCHK) {
            int row = c / ROWC;
            int c4  = c - row * ROWC;
            int g0  = min(max(ws + c4 * 4, 0), NPOS - 4);
            gload16(kg + (size_t)row * NPOS + g0, buf + c * 4);
        }
    }
#pragma unroll
    for (int it = 0; it < 5; ++it) {
        int c = it * 256 + (int)threadIdx.x;
        if (c < NCHK) {
            int row = c / ROWC;
            int c4  = c - row * ROWC;
            int g0  = min(max(ws + c4 * 4, 0), NPOS - 4);
            gload16(vg + (size_t)row * NPOS + g0, buf + (NCHK + c) * 4);
        }
    }
}

// q for one tile: 4 global_load_dwordx4 per wave into registers.
__device__ __forceinline__ void load_q(const float* qg, int n0, int cs,
                                       float4* qv) {
#pragma unroll
    for (int i = 0; i < CPT; ++i)
        qv[i] = *(const float4*)(qg + (size_t)(cs * CPT + i) * NPOS + n0);
}

// Load a 28-float window (7 x ds_read_b128) from an LDS row.
__device__ __forceinline__ void load_w(const float* base, float* w) {
    const float4* wp = (const float4*)base;
#pragma unroll
    for (int u = 0; u < WSPAN / 4; ++u) {
        float4 x = wp[u];
        w[4*u] = x.x; w[4*u+1] = x.y; w[4*u+2] = x.z; w[4*u+3] = x.w;
    }
}

// QK^T partials + 8-lane reduce.
__device__ __forceinline__ void qk_pass(const float* ksb, int cs, int lg,
                                        const float4* qv, float s[TPT][KW]) {
#pragma unroll
    for (int t = 0; t < TPT; ++t)
#pragma unroll
        for (int j = 0; j < KW; ++j) s[t][j] = 0.0f;
#pragma unroll
    for (int i = 0; i < CPT; ++i) {
        int row = cs * CPT + i;
        float w[WSPAN];
        load_w(ksb + row * SLDS + lg * TPT, w);
        float qt[TPT] = {qv[i].x, qv[i].y, qv[i].z, qv[i].w};
#pragma unroll
        for (int t = 0; t < TPT; ++t)
#pragma unroll
            for (int j = 0; j < KW; ++j)
                s[t][j] = fmaf(qt[t], w[t + 3*j], s[t][j]);
    }
#pragma unroll
    for (int t = 0; t < TPT; ++t)
#pragma unroll
        for (int j = 0; j < KW; ++j)
            s[t][j] = dpp_sum8(s[t][j]);
}

// Softmax over the 9 taps of each owned token. masked is block-uniform.
__device__ __forceinline__ void softmax9(float s[TPT][KW], int n0, bool masked) {
    const float scale = 0.17677669529663687f;    // 32^-0.5
    if (!masked) {
#pragma unroll
        for (int t = 0; t < TPT; ++t) {
            float m = -INFINITY;
#pragma unroll
            for (int j = 0; j < KW; ++j) {
                float x = s[t][j] * scale;
                s[t][j] = x;
                m = fmaxf(m, x);
            }
            float sum = 0.0f;
#pragma unroll
            for (int j = 0; j < KW; ++j) {
                float e = __expf(s[t][j] - m);
                s[t][j] = e;
                sum += e;
            }
            float inv = 1.0f / sum;
#pragma unroll
            for (int j = 0; j < KW; ++j) s[t][j] *= inv;
        }
    } else {
        // invalid taps: logit exactly 0 (Unfold zero-padding), prob zeroed
#pragma unroll
        for (int t = 0; t < TPT; ++t) {
            float vm[KW];
            float m = -INFINITY;
#pragma unroll
            for (int j = 0; j < KW; ++j) {
                vm[j] = ((unsigned)(n0 + t + 3*j - PAD) < NPOS) ? 1.0f : 0.0f;
                float x = s[t][j] * scale * vm[j];
                s[t][j] = x;
                m = fmaxf(m, x);
            }
            float sum = 0.0f;
#pragma unroll
            for (int j = 0; j < KW; ++j) {
                float e = __expf(s[t][j] - m);
                s[t][j] = e;
                sum += e;
            }
            float inv = 1.0f / sum;
#pragma unroll
            for (int j = 0; j < KW; ++j)
                s[t][j] *= inv * vm[j];
        }
    }
}

// P·V accumulate.
__device__ __forceinline__ void pv_pass(const float* vsb, int cs, int lg,
                                        const float s[TPT][KW], float o[TPT][CPT]) {
#pragma unroll
    for (int t = 0; t < TPT; ++t)
#pragma unroll
        for (int i = 0; i < CPT; ++i) o[t][i] = 0.0f;
#pragma unroll
    for (int i = 0; i < CPT; ++i) {
        int row = cs * CPT + i;
        float w[WSPAN];
        load_w(vsb + row * SLDS + lg * TPT, w);
#pragma unroll
        for (int t = 0; t < TPT; ++t)
#pragma unroll
            for (int j = 0; j < KW; ++j)
                o[t][i] = fmaf(s[t][j], w[t + 3*j], o[t][i]);
    }
}

__global__ __launch_bounds__(256) void dilate_attn_kernel(
    const float* __restrict__ q,
    const float* __restrict__ k,
    const float* __restrict__ v,
    float* __restrict__ out)
{
    // Double-buffered staging: 2 sets x (k rows + v rows). 79872 B -> 2 blk/CU.
    __shared__ float kvb[2][BUFSZ];

    const int bh = blockIdx.x >> 3;            // 0..63  (b*16+h)
    const int tb = blockIdx.x & (NBLK - 1);    // 0..7   block's tile quartet
    const int t0 = tb * TPB;                   // first tile index

    const size_t cb = (size_t)bh * HD * NPOS;
    const float* qg = q + cb;
    const float* kg = k + cb;
    const float* vg = v + cb;

    const int cs = threadIdx.x & (CSPL - 1);   // lane&7: channel octet slot
    const int lg = threadIdx.x >> 3;           // token group in tile
    const int b  = bh >> 4;
    const int hh = bh & (NH - 1);

    float4 qA[CPT], qB[CPT];

    // ---- prologue: issue tile t0's K,V (LDS) + q (regs): 14 vmem/wave ----
    stage_kv(kg, vg, t0 * TILE - PAD, kvb[0]);
    load_q(qg, t0 * TILE + lg * TPT, cs, qA);
    asm volatile("" ::: "memory");

#pragma unroll
    for (int t = 0; t < TPB; ++t) {
        const int tile = t0 + t;
        const int n0   = tile * TILE + lg * TPT;
        float* buf = kvb[t & 1];

        // ---- issue tile t+1's batch first: overlaps with compute(t) ------
        if (t < TPB - 1) {
            stage_kv(kg, vg, (tile + 1) * TILE - PAD, kvb[(t + 1) & 1]);
            if (t & 1) load_q(qg, (tile + 1) * TILE + lg * TPT, cs, qA);
            else       load_q(qg, (tile + 1) * TILE + lg * TPT, cs, qB);
        }
        // ---- drain tile t's 14 loads; keep t+1's loads + old stores live --
        // vmcnt in-order: 18 = stores(4, prev iter) + next batch(14).
        if (t == 0)           asm volatile("s_waitcnt vmcnt(14)" ::: "memory");
        else if (t < TPB - 1) asm volatile("s_waitcnt vmcnt(18)" ::: "memory");
        else                  asm volatile("s_waitcnt vmcnt(4)"  ::: "memory");
        __builtin_amdgcn_s_barrier();          // all waves' staging visible
        asm volatile("" ::: "memory");

        // ---- compute tile t -----------------------------------------------
        float s[TPT][KW];
        float o[TPT][CPT];
        if (t & 1) qk_pass(buf, cs, lg, qB, s);
        else       qk_pass(buf, cs, lg, qA, s);
        softmax9(s, n0, tile == 0 || tile == NTILES - 1);
        pv_pass(buf + HD * SLDS, cs, lg, s, o);

        // ---- store (4 dwordx4/wave; completion not waited in main loop) ---
#pragma unroll
        for (int tt = 0; tt < TPT; ++tt) {
            float* op = out + ((size_t)(b * NPOS + n0 + tt)) * DCH
                        + hh * HD + cs * CPT;
            *(float4*)op = make_float4(o[tt][0], o[tt][1], o[tt][2], o[tt][3]);
        }
        asm volatile("" ::: "memory");
        __builtin_amdgcn_s_barrier();          // buf[t&1] free for overwrite
        asm volatile("" ::: "memory");
    }
}

extern "C" void kernel_launch(void* const* d_in, const int* in_sizes, int n_in,
                              void* d_out, int out_size, void* d_ws, size_t ws_size,
                              hipStream_t stream) {
    const float* q = (const float*)d_in[0];
    const float* k = (const float*)d_in[1];
    const float* v = (const float*)d_in[2];
    float* out = (float*)d_out;

    const int grid = 4 * NH * NBLK;     // 64 bh * 8 = 512 persistent blocks
    hipLaunchKernelGGL(dilate_attn_kernel, dim3(grid), dim3(256), 0, stream,
                       q, k, v, out);
}

// Round 7
// 133.584 us; speedup vs baseline: 1.3365x; 1.0591x over previous
//
#include <hip/hip_runtime.h>
#include <math.h>

#define NPOS 4096
#define DCH  512
#define HD   32
#define NH   16
#define KW   9
#define DIL  3
#define PAD  12
#define TILE   128
#define NTILES (NPOS / TILE)       // 32
#define SPANT  (TILE + 2*PAD)      // 152 tokens staged per tile
#define ROWF4  (SPANT / 4)         // 38 real float4 per channel row
#define SLDS   156                 // LDS row stride in floats (152 + 4 pad)
#define ROWC   (SLDS / 4)          // 39 16B chunks per row (incl pad chunk)
#define NCHK   (HD * ROWC)         // 1248 chunks per buffer (k or v)
#define CSPL   8                   // channel-split lanes per token-group
#define CPT    (HD / CSPL)         // 4 channels per thread
#define TPT    4                   // tokens per thread
#define WSPAN  28                  // 4 tokens x 9 taps span 28 tokens
#define NXCD   8

// Native clang vector for nontemporal builtin (HIP float4 is a class type).
typedef float floatx4 __attribute__((ext_vector_type(4)));

// Direct global->LDS (16B).
__device__ __forceinline__ void gload16(const float* g, float* l) {
    __builtin_amdgcn_global_load_lds(
        (const __attribute__((address_space(1))) void*)g,
        (__attribute__((address_space(3))) void*)l,
        16, 0, 0);
}

// Butterfly sum over 8 consecutive lanes — pure VALU via DPP.
__device__ __forceinline__ float dpp_sum8(float x) {
    int t;
    t = __builtin_amdgcn_update_dpp(0, __float_as_int(x), 0xB1, 0xF, 0xF, true);
    x += __int_as_float(t);
    t = __builtin_amdgcn_update_dpp(0, __float_as_int(x), 0x4E, 0xF, 0xF, true);
    x += __int_as_float(t);
    t = __builtin_amdgcn_update_dpp(0, __float_as_int(x), 0x141, 0xF, 0xF, true);
    x += __int_as_float(t);
    return x;
}

// Load 28-float window (7 x ds_read_b128) from an LDS row.
__device__ __forceinline__ void load_w(const float* base, float* w) {
    const float4* wp = (const float4*)base;
#pragma unroll
    for (int u = 0; u < WSPAN / 4; ++u) {
        float4 x = wp[u];
        w[4*u] = x.x; w[4*u+1] = x.y; w[4*u+2] = x.z; w[4*u+3] = x.w;
    }
}

// QK^T partials + 8-lane reduce.
__device__ __forceinline__ void qk_pass(const float* ksb, int cs, int lg,
                                        const float4* qv, float s[TPT][KW]) {
#pragma unroll
    for (int t = 0; t < TPT; ++t)
#pragma unroll
        for (int j = 0; j < KW; ++j) s[t][j] = 0.0f;
#pragma unroll
    for (int i = 0; i < CPT; ++i) {
        int row = cs * CPT + i;
        float w[WSPAN];
        load_w(ksb + row * SLDS + lg * TPT, w);
        float qt[TPT] = {qv[i].x, qv[i].y, qv[i].z, qv[i].w};
#pragma unroll
        for (int t = 0; t < TPT; ++t)
#pragma unroll
            for (int j = 0; j < KW; ++j)
                s[t][j] = fmaf(qt[t], w[t + 3*j], s[t][j]);
    }
#pragma unroll
    for (int t = 0; t < TPT; ++t)
#pragma unroll
        for (int j = 0; j < KW; ++j)
            s[t][j] = dpp_sum8(s[t][j]);
}

// P·V accumulate.
__device__ __forceinline__ void pv_pass(const float* vsb, int cs, int lg,
                                        const float s[TPT][KW], float o[TPT][CPT]) {
#pragma unroll
    for (int t = 0; t < TPT; ++t)
#pragma unroll
        for (int i = 0; i < CPT; ++i) o[t][i] = 0.0f;
#pragma unroll
    for (int i = 0; i < CPT; ++i) {
        int row = cs * CPT + i;
        float w[WSPAN];
        load_w(vsb + row * SLDS + lg * TPT, w);
#pragma unroll
        for (int t = 0; t < TPT; ++t)
#pragma unroll
            for (int j = 0; j < KW; ++j)
                o[t][i] = fmaf(s[t][j], w[t + 3*j], o[t][i]);
    }
}

__global__ __launch_bounds__(256) void dilate_attn_kernel(
    const float* __restrict__ q,
    const float* __restrict__ k,
    const float* __restrict__ v,
    float* __restrict__ out)
{
    // Single contiguous buffer: k rows then v rows (chunk-linear for gload16).
    __shared__ float kv[2 * HD * SLDS];
    float* const ks = kv;
    float* const vs = kv + HD * SLDS;

    // ---- XCD-aware remap: all 32 tiles of a bh land on ONE XCD ------------
    // HW round-robins consecutive blockIdx across XCDs (id % 8 = XCD).
    // id = xcd + 8*seq; seq = bhi*32 + tile; bh = bhi*8 + xcd.
    // => same bh -> same xcd; consecutive tiles consecutive in seq.
    const int id   = blockIdx.x;
    const int xcd  = id & (NXCD - 1);
    const int seq  = id >> 3;                    // 0..255
    const int tile = seq & (NTILES - 1);         // 0..31
    const int bh   = ((seq >> 5) << 3) | xcd;    // 0..63

    const int n0t  = tile * TILE;                // first token of tile
    const int ws   = n0t - PAD;                  // staged span start (may be <0)

    const size_t cb = (size_t)bh * HD * NPOS;
    const float* kg = k + cb;
    const float* vg = v + cb;
    const float* qg = q + cb;

    const int cs = threadIdx.x & (CSPL - 1);     // lane&7: channel octet slot
    const int lg = threadIdx.x >> 3;             // 0..31: token group in tile
    const int n0 = n0t + lg * TPT;               // first token this thread owns

    // easy <=> staged span fully interior <=> ALL taps of ALL tile tokens valid
    const bool easy = (ws >= 0) && (ws + SPANT <= NPOS);
    const float scale = 0.17677669529663687f;    // 32^-0.5

    float4 qv[CPT];
    float  s[TPT][KW];
    float  o[TPT][CPT];

    if (easy) {
        // ---- issue order matters for counted vmcnt: q (oldest), K, V ------
#pragma unroll
        for (int i = 0; i < CPT; ++i)
            qv[i] = *(const float4*)(qg + (size_t)(cs * CPT + i) * NPOS + n0);
        asm volatile("" ::: "memory");           // pin q before K
#pragma unroll
        for (int it = 0; it < 5; ++it) {
            int c = it * 256 + (int)threadIdx.x;
            if (c < NCHK) {
                int row = c / ROWC;
                int c4  = c - row * ROWC;
                gload16(kg + (size_t)row * NPOS + (ws + c4 * 4), &kv[c * 4]);
            }
        }
        asm volatile("" ::: "memory");           // pin K before V
#pragma unroll
        for (int it = 0; it < 5; ++it) {
            int c = it * 256 + (int)threadIdx.x;
            if (c < NCHK) {
                int row = c / ROWC;
                int c4  = c - row * ROWC;
                gload16(vg + (size_t)row * NPOS + (ws + c4 * 4),
                        &kv[(NCHK + c) * 4]);
            }
        }
        // Wait own q(4)+K(5) retired; V(5) stays in flight under pass 1.
        asm volatile("s_waitcnt vmcnt(5)" ::: "memory");
        __builtin_amdgcn_s_barrier();            // all waves' K visible
        asm volatile("" ::: "memory");

        // ---- pass 1 + softmax, V staging overlapped underneath -------------
        qk_pass(ks, cs, lg, qv, s);
#pragma unroll
        for (int t = 0; t < TPT; ++t) {
            float m = -INFINITY;
#pragma unroll
            for (int j = 0; j < KW; ++j) {
                float x = s[t][j] * scale;
                s[t][j] = x;
                m = fmaxf(m, x);
            }
            float sum = 0.0f;
#pragma unroll
            for (int j = 0; j < KW; ++j) {
                float e = __expf(s[t][j] - m);
                s[t][j] = e;
                sum += e;
            }
            float inv = 1.0f / sum;
#pragma unroll
            for (int j = 0; j < KW; ++j) s[t][j] *= inv;
        }

        asm volatile("s_waitcnt vmcnt(0)" ::: "memory");
        __builtin_amdgcn_s_barrier();
        asm volatile("" ::: "memory");

        pv_pass(vs, cs, lg, s, o);
    } else {
        // ---- edge tiles (2 of 32): clamped scalar staging, full drain ------
        for (int p = threadIdx.x; p < HD * ROWF4; p += 256) {
            int row = p / ROWF4;
            int c4  = p - row * ROWF4;
            int g0  = ws + c4 * 4;
            const float* kr = kg + (size_t)row * NPOS;
            const float* vr = vg + (size_t)row * NPOS;
            float4 kk, vv;
            if (g0 >= 0 && g0 + 4 <= NPOS) {
                kk = *(const float4*)(kr + g0);
                vv = *(const float4*)(vr + g0);
            } else {
                int i0 = min(max(g0 + 0, 0), NPOS - 1);
                int i1 = min(max(g0 + 1, 0), NPOS - 1);
                int i2 = min(max(g0 + 2, 0), NPOS - 1);
                int i3 = min(max(g0 + 3, 0), NPOS - 1);
                kk = make_float4(kr[i0], kr[i1], kr[i2], kr[i3]);
                vv = make_float4(vr[i0], vr[i1], vr[i2], vr[i3]);
            }
            *(float4*)&ks[row * SLDS + c4 * 4] = kk;
            *(float4*)&vs[row * SLDS + c4 * 4] = vv;
        }
#pragma unroll
        for (int i = 0; i < CPT; ++i)
            qv[i] = *(const float4*)(qg + (size_t)(cs * CPT + i) * NPOS + n0);

        __syncthreads();

        qk_pass(ks, cs, lg, qv, s);
        // invalid taps: logit exactly 0 (Unfold zero-padding), prob zeroed
#pragma unroll
        for (int t = 0; t < TPT; ++t) {
            float vm[KW];
            float m = -INFINITY;
#pragma unroll
            for (int j = 0; j < KW; ++j) {
                vm[j] = ((unsigned)(n0 + t + 3*j - PAD) < NPOS) ? 1.0f : 0.0f;
                float x = s[t][j] * scale * vm[j];
                s[t][j] = x;
                m = fmaxf(m, x);
            }
            float sum = 0.0f;
#pragma unroll
            for (int j = 0; j < KW; ++j) {
                float e = __expf(s[t][j] - m);
                s[t][j] = e;
                sum += e;
            }
            float inv = 1.0f / sum;
#pragma unroll
            for (int j = 0; j < KW; ++j)
                s[t][j] *= inv * vm[j];
        }
        pv_pass(vs, cs, lg, s, o);
    }

    // ---- Store: one float4 per token, NON-TEMPORAL (write-only data; ------
    // keep it from evicting k/v/q from L2/L3) --------------------------------
    const int b  = bh >> 4;
    const int hh = bh & (NH - 1);
#pragma unroll
    for (int t = 0; t < TPT; ++t) {
        float* op = out + ((size_t)(b * NPOS + n0 + t)) * DCH + hh * HD + cs * CPT;
        floatx4 val = {o[t][0], o[t][1], o[t][2], o[t][3]};
        __builtin_nontemporal_store(val, (floatx4*)op);
    }
}

extern "C" void kernel_launch(void* const* d_in, const int* in_sizes, int n_in,
                              void* d_out, int out_size, void* d_ws, size_t ws_size,
                              hipStream_t stream) {
    const float* q = (const float*)d_in[0];
    const float* k = (const float*)d_in[1];
    const float* v = (const float*)d_in[2];
    float* out = (float*)d_out;

    const int grid = 4 * NH * NTILES;   // 64 bh * 32 tiles = 2048 blocks
    hipLaunchKernelGGL(dilate_attn_kernel, dim3(grid), dim3(256), 0, stream,
                       q, k, v, out);
}

// Round 8
// 132.381 us; speedup vs baseline: 1.3486x; 1.0091x over previous
//
#include <hip/hip_runtime.h>
#include <math.h>

#define NPOS 4096
#define DCH  512
#define HD   32
#define NH   16
#define KW   9
#define DIL  3
#define PAD  12
#define TILE   32                  // tokens per block == per wave
#define NTILES (NPOS / TILE)       // 128
#define SPANT  (TILE + 2*PAD)      // 56 tokens staged per wave
#define RS     60                  // LDS row stride floats (56 + 4 pad).
                                   // 60 % 32 = 28 -> strided ds_read_b128 is 2-way (free);
                                   // 15 chunks/row makes chunk c -> float 4c EXACTLY LINEAR
                                   // (row*60 + c4*4 = 4*(15*row + c4)) as gload16 requires.
#define ROWC   (RS / 4)            // 15 16B chunks per row
#define NCHK   (2 * HD * ROWC)     // 960 chunks: K rows 0..31 then V rows 32..63
#define NINST  (NCHK / 64)         // 15 staging insts per wave (exact, no tail)
#define CSPL   8                   // channel-split lanes per token-group
#define CPT    (HD / CSPL)         // 4 channels per thread
#define TPT    4                   // tokens per thread (8 groups x 4)
#define WSPAN  28                  // 4 tokens x 9 taps span 28 tokens
#define NXCD   8

// Native clang vector for nontemporal builtin (HIP float4 is a class type).
typedef float floatx4 __attribute__((ext_vector_type(4)));

// Direct global->LDS (16B). LDS dest must be linear in lane: we pass &kv[4*c]
// with c = it*64 + lane.
__device__ __forceinline__ void gload16(const float* g, float* l) {
    __builtin_amdgcn_global_load_lds(
        (const __attribute__((address_space(1))) void*)g,
        (__attribute__((address_space(3))) void*)l,
        16, 0, 0);
}

// Butterfly sum over 8 consecutive lanes — pure VALU via DPP.
__device__ __forceinline__ float dpp_sum8(float x) {
    int t;
    t = __builtin_amdgcn_update_dpp(0, __float_as_int(x), 0xB1, 0xF, 0xF, true);
    x += __int_as_float(t);
    t = __builtin_amdgcn_update_dpp(0, __float_as_int(x), 0x4E, 0xF, 0xF, true);
    x += __int_as_float(t);
    t = __builtin_amdgcn_update_dpp(0, __float_as_int(x), 0x141, 0xF, 0xF, true);
    x += __int_as_float(t);
    return x;
}

// Load 28-float window (7 x ds_read_b128) from an LDS row.
__device__ __forceinline__ void load_w(const float* base, float* w) {
    const float4* wp = (const float4*)base;
#pragma unroll
    for (int u = 0; u < WSPAN / 4; ++u) {
        float4 x = wp[u];
        w[4*u] = x.x; w[4*u+1] = x.y; w[4*u+2] = x.z; w[4*u+3] = x.w;
    }
}

__global__ __launch_bounds__(64) void dilate_attn_kernel(
    const float* __restrict__ q,
    const float* __restrict__ k,
    const float* __restrict__ v,
    float* __restrict__ out)
{
    // Per-wave private staging: K rows then V rows, chunk-linear. 15360 B.
    __shared__ float kv[2 * HD * RS];

    // ---- XCD-aware remap: all 128 tiles of a bh land on ONE XCD, ----------
    // consecutive tiles consecutive in dispatch (halo lines L2-hot).
    const int id   = blockIdx.x;
    const int xcd  = id & (NXCD - 1);
    const int seq  = id >> 3;                    // 0..1023
    const int tile = seq & (NTILES - 1);         // 0..127
    const int bh   = ((seq >> 7) << 3) | xcd;    // 0..63

    const int n0t  = tile * TILE;
    const int ws   = n0t - PAD;                  // staged span start (may be <0)

    const size_t cb = (size_t)bh * HD * NPOS;
    const float* qg = q + cb;
    const float* kg = k + cb;
    const float* vg = v + cb;

    const int tid = threadIdx.x;                 // 0..63 (one wave)
    const int cs  = tid & (CSPL - 1);            // channel octet slot
    const int lg  = tid >> 3;                    // 0..7: token group
    const int n0  = n0t + lg * TPT;              // first token this thread owns

    const float scale = 0.17677669529663687f;    // 32^-0.5

    // ---- issue q first (4 insts, oldest in vmcnt order) --------------------
    float4 qv[CPT];
#pragma unroll
    for (int i = 0; i < CPT; ++i)
        qv[i] = *(const float4*)(qg + (size_t)(cs * CPT + i) * NPOS + n0);
    asm volatile("" ::: "memory");               // pin q before KV

    // ---- stage K+V span: 15 x global_load_lds_dwordx4, no barrier ever -----
    // Per-lane global src CLAMPED to [0, NPOS-4]: clamp fires only on chunks
    // whose taps are ALL invalid (boundary aligns: ws % 4 == 0), masked to
    // exact zero in softmax below.
#pragma unroll
    for (int it = 0; it < NINST; ++it) {
        int c   = it * 64 + tid;                 // 0..959
        int row = c / ROWC;                      // 0..63 (K: 0..31, V: 32..63)
        int c4  = c - row * ROWC;                // 0..14
        int g0  = min(max(ws + c4 * 4, 0), NPOS - 4);
        const float* src = (row < HD)
            ? kg + (size_t)row * NPOS + g0
            : vg + (size_t)(row - HD) * NPOS + g0;
        gload16(src, &kv[c * 4]);                // LDS dest linear in lane
    }

    // ---- wait own q(4) + K-covering insts(8) of 19 total: vmcnt(7) --------
    // K chunks 0..479 are covered by staging insts 0..7 (chunks 0..511).
    asm volatile("s_waitcnt vmcnt(7)" ::: "memory");

    // ---- Pass 1: scores from own LDS K (V still in flight underneath) -----
    float s[TPT][KW];
#pragma unroll
    for (int t = 0; t < TPT; ++t)
#pragma unroll
        for (int j = 0; j < KW; ++j) s[t][j] = 0.0f;

#pragma unroll
    for (int i = 0; i < CPT; ++i) {
        int row = cs * CPT + i;
        float w[WSPAN];
        load_w(&kv[row * RS + lg * TPT], w);     // window local start = lg*4
        float qt[TPT] = {qv[i].x, qv[i].y, qv[i].z, qv[i].w};
#pragma unroll
        for (int t = 0; t < TPT; ++t)
#pragma unroll
            for (int j = 0; j < KW; ++j)
                s[t][j] = fmaf(qt[t], w[t + 3*j], s[t][j]);
    }

    // Reduce partials across the 8 channel-split lanes (DPP, no DS ops)
#pragma unroll
    for (int t = 0; t < TPT; ++t)
#pragma unroll
        for (int j = 0; j < KW; ++j)
            s[t][j] = dpp_sum8(s[t][j]);

    // ---- Softmax (tap-mask only for the two edge tiles; wave-uniform) -----
    const bool masked = (tile == 0) || (tile == NTILES - 1);
    if (!masked) {
#pragma unroll
        for (int t = 0; t < TPT; ++t) {
            float m = -INFINITY;
#pragma unroll
            for (int j = 0; j < KW; ++j) {
                float x = s[t][j] * scale;
                s[t][j] = x;
                m = fmaxf(m, x);
            }
            float sum = 0.0f;
#pragma unroll
            for (int j = 0; j < KW; ++j) {
                float e = __expf(s[t][j] - m);
                s[t][j] = e;
                sum += e;
            }
            float inv = 1.0f / sum;
#pragma unroll
            for (int j = 0; j < KW; ++j) s[t][j] *= inv;
        }
    } else {
        // invalid taps: logit exactly 0 (Unfold zero-padding), prob zeroed
#pragma unroll
        for (int t = 0; t < TPT; ++t) {
            float vm[KW];
            float m = -INFINITY;
#pragma unroll
            for (int j = 0; j < KW; ++j) {
                vm[j] = ((unsigned)(n0 + t + 3*j - PAD) < NPOS) ? 1.0f : 0.0f;
                float x = s[t][j] * scale * vm[j];
                s[t][j] = x;
                m = fmaxf(m, x);
            }
            float sum = 0.0f;
#pragma unroll
            for (int j = 0; j < KW; ++j) {
                float e = __expf(s[t][j] - m);
                s[t][j] = e;
                sum += e;
            }
            float inv = 1.0f / sum;
#pragma unroll
            for (int j = 0; j < KW; ++j)
                s[t][j] *= inv * vm[j];
        }
    }

    // ---- own V retired (no barrier: this wave wrote and reads it) ---------
    asm volatile("s_waitcnt vmcnt(0)" ::: "memory");

    // ---- Pass 2: output from own LDS V -------------------------------------
    float o[TPT][CPT];
#pragma unroll
    for (int t = 0; t < TPT; ++t)
#pragma unroll
        for (int i = 0; i < CPT; ++i) o[t][i] = 0.0f;

#pragma unroll
    for (int i = 0; i < CPT; ++i) {
        int row = cs * CPT + i;
        float w[WSPAN];
        load_w(&kv[(HD + row) * RS + lg * TPT], w);
#pragma unroll
        for (int t = 0; t < TPT; ++t)
#pragma unroll
            for (int j = 0; j < KW; ++j)
                o[t][i] = fmaf(s[t][j], w[t + 3*j], o[t][i]);
    }

    // ---- Store: one NT float4 per token (128B/token across 8 cs lanes) ----
    const int b  = bh >> 4;
    const int hh = bh & (NH - 1);
#pragma unroll
    for (int t = 0; t < TPT; ++t) {
        float* op = out + ((size_t)(b * NPOS + n0 + t)) * DCH + hh * HD + cs * CPT;
        floatx4 val = {o[t][0], o[t][1], o[t][2], o[t][3]};
        __builtin_nontemporal_store(val, (floatx4*)op);
    }
}

extern "C" void kernel_launch(void* const* d_in, const int* in_sizes, int n_in,
                              void* d_out, int out_size, void* d_ws, size_t ws_size,
                              hipStream_t stream) {
    const float* q = (const float*)d_in[0];
    const float* k = (const float*)d_in[1];
    const float* v = (const float*)d_in[2];
    float* out = (float*)d_out;

    const int grid = 4 * NH * NTILES;   // 64 bh * 128 tiles = 8192 one-wave blocks
    hipLaunchKernelGGL(dilate_attn_kernel, dim3(grid), dim3(64), 0, stream,
                       q, k, v, out);
}